// Round 6
// baseline (2175.540 us; speedup 1.0000x reference)
//
#include <hip/hip_runtime.h>
#include <cstddef>
#include <cstdint>

#define N_NODES 5120
#define E_EDGES 163840
#define F 256
#define TSTEPS 24
#define ND 1024          // GEMM N = 4*256 (gates, column-permuted)
#define XROWSTRIDE 6144  // T*F

typedef unsigned short u16;
typedef unsigned int u32;
typedef __bf16 bf16x8 __attribute__((ext_vector_type(8)));
typedef float f32x4 __attribute__((ext_vector_type(4)));

__device__ __forceinline__ u16 f2bf(float f) {
    u32 u = __float_as_uint(f);
    u = (u + 0x7FFFu + ((u >> 16) & 1u)) >> 16;  // round-to-nearest-even
    return (u16)u;
}
__device__ __forceinline__ float bf2f(u16 h) {
    return __uint_as_float((u32)h << 16);
}
__device__ __forceinline__ float fsigmoid(float x) {
    return 1.f / (1.f + __expf(-x));
}
__device__ __forceinline__ float ftanh(float x) {
    // tanh(x) = 1 - 2/(exp(2x)+1); saturates correctly for |x| large
    return 1.f - 2.f / (__expf(2.f * x) + 1.f);
}

// ---------------- graph preprocessing ----------------

__global__ void deg_kernel(const float* __restrict__ ew, const int* __restrict__ src,
                           float* __restrict__ deg) {
    int e = blockIdx.x * 256 + threadIdx.x;
    if (e < E_EDGES) atomicAdd(&deg[src[e]], ew[e]);
}

__global__ void dis_kernel(float* __restrict__ deg) {
    int n = blockIdx.x * 256 + threadIdx.x;
    if (n < N_NODES) {
        float d = deg[n];
        deg[n] = d > 0.f ? rsqrtf(d) : 0.f;
    }
}

__global__ void count_kernel(const int* __restrict__ dst, int* __restrict__ cnt) {
    int e = blockIdx.x * 256 + threadIdx.x;
    if (e < E_EDGES) atomicAdd(&cnt[dst[e]], 1);
}

// one block, 256 threads, 20 counts each (N_NODES = 256*20)
__global__ void scan_kernel(const int* __restrict__ cnt, int* __restrict__ row_ptr) {
    __shared__ int s[256];
    int tid = threadIdx.x;
    int base = tid * 20;
    int local[20];
    int sum = 0;
    #pragma unroll
    for (int i = 0; i < 20; i++) { local[i] = sum; sum += cnt[base + i]; }
    s[tid] = sum;
    __syncthreads();
    for (int off = 1; off < 256; off <<= 1) {
        int v = (tid >= off) ? s[tid - off] : 0;
        __syncthreads();
        s[tid] += v;
        __syncthreads();
    }
    int offset = (tid == 0) ? 0 : s[tid - 1];
    #pragma unroll
    for (int i = 0; i < 20; i++) row_ptr[base + i] = offset + local[i];
    if (tid == 0) row_ptr[N_NODES] = E_EDGES;
}

__global__ void fill_csr(const int* __restrict__ src, const int* __restrict__ dst,
                         const float* __restrict__ ew, const float* __restrict__ dis,
                         const int* __restrict__ row_ptr, int* __restrict__ cursor,
                         int* __restrict__ csr_src, float* __restrict__ csr_w) {
    int e = blockIdx.x * 256 + threadIdx.x;
    if (e >= E_EDGES) return;
    int s = src[e], d = dst[e];
    int pos = row_ptr[d] + atomicAdd(&cursor[d], 1);
    csr_src[pos] = s;
    // w_hat = (2/lambda_max)*(-dis[src]*w*dis[dst]); lambda_max=2 -> factor 1
    csr_w[pos] = -dis[s] * ew[e] * dis[d];
}

// Column permutation: col'(g, j) = (j>>4)*64 + g*16 + (j&15).
// Inverse: g = (c>>4)&3, j = (c>>6)*16 + (c&15).
// WT[c'][k] (bf16, k contiguous) = Wcat[k][g*256+j]
__global__ void build_wcatT(const float* __restrict__ Ws, const float* __restrict__ thetas,
                            u16* __restrict__ WT) {
    int idx = blockIdx.x * 256 + threadIdx.x;
    if (idx >= 1024 * 1024) return;
    int c = idx >> 10, k = idx & 1023;
    int g = (c >> 4) & 3;
    int j = (c >> 6) * 16 + (c & 15);
    float v;
    if (k < 256) {
        v = Ws[(g * 256 + k) * 256 + j];
    } else {
        int kc = (k >> 8) - 1;  // 0..2
        int rr = k & 255;
        v = thetas[((g * 3 + kc) * 256 + rr) * 256 + j];
    }
    WT[idx] = f2bf(v);
}

// bsum[c'] = bs[g*256+j] + cbs[g*256+j] in permuted column order
__global__ void build_bsum(const float* __restrict__ bs, const float* __restrict__ cbs,
                           float* __restrict__ bsum) {
    int c = blockIdx.x * 256 + threadIdx.x;
    if (c >= 1024) return;
    int g = (c >> 4) & 3;
    int j = (c >> 6) * 16 + (c & 15);
    bsum[c] = bs[g * 256 + j] + cbs[g * 256 + j];
}

// ---------------- prop: wave-per-node edge gather ----------------

__global__ __launch_bounds__(256) void prop_kernel(
        const u16* __restrict__ xin, const u16* __restrict__ sub, float scale,
        const int* __restrict__ row_ptr, const int* __restrict__ csr_src,
        const float* __restrict__ csr_w, u16* __restrict__ out_bf,
        const float* __restrict__ X, int t, u16* __restrict__ xt_out) {
    __shared__ int s_src[4][64];
    __shared__ float s_w[4][64];
    int wid = threadIdx.x >> 6, l = threadIdx.x & 63;
    int n = blockIdx.x * 4 + wid;
    int start = row_ptr[n], end = row_ptr[n + 1];
    float acc0 = 0.f, acc1 = 0.f, acc2 = 0.f, acc3 = 0.f;
    int fb = l * 4;  // this lane's 4 features
    for (int base = start; base < end; base += 64) {
        int chunk = min(64, end - base);
        if (l < chunk) {
            s_src[wid][l] = csr_src[base + l];
            s_w[wid][l] = csr_w[base + l];
        }
        #pragma unroll 4
        for (int i = 0; i < chunk; i++) {
            int s = s_src[wid][i];
            float wt = s_w[wid][i];
            ushort4 hv = *(const ushort4*)(xin + (size_t)s * F + fb);
            acc0 += wt * bf2f(hv.x);
            acc1 += wt * bf2f(hv.y);
            acc2 += wt * bf2f(hv.z);
            acc3 += wt * bf2f(hv.w);
        }
    }
    size_t o = (size_t)n * F + fb;
    float r0 = scale * acc0, r1 = scale * acc1, r2 = scale * acc2, r3 = scale * acc3;
    if (sub) {
        ushort4 sv = *(const ushort4*)(sub + o);
        r0 -= bf2f(sv.x); r1 -= bf2f(sv.y); r2 -= bf2f(sv.z); r3 -= bf2f(sv.w);
    }
    ushort4 ov;
    ov.x = f2bf(r0); ov.y = f2bf(r1); ov.z = f2bf(r2); ov.w = f2bf(r3);
    *(ushort4*)(out_bf + o) = ov;
    if (xt_out) {
        float4 xv = *(const float4*)(X + (size_t)n * XROWSTRIDE + (size_t)t * F + fb);
        ushort4 xo;
        xo.x = f2bf(xv.x); xo.y = f2bf(xv.y); xo.z = f2bf(xv.z); xo.w = f2bf(xv.w);
        *(ushort4*)(xt_out + o) = xo;
    }
}

// ---------------- LDS-free reg-streaming bf16 MFMA GEMM + LSTM epilogue ----------------
// Tile 64x128, wave sub-tile 32x64, grid 80x8 = 640 blocks.
// No LDS, no barriers: MFMA fragments load straight from global to VGPRs.
// A-frag: lane l reads A[base+(l&15)][kw*32+(l>>4)*8 .. +7] -> 64 lanes cover
// 16 complete 64B lines (100% utilization, fully coalesced). B identical from
// WT[col][1024] (k-contiguous). Window byte offsets (<=448) fold into imm.
#define GBM 64
#define GBN 128

__global__ __launch_bounds__(256, 3) void mfma_gemm(
        const u16* __restrict__ Xt, const u16* __restrict__ Hb,
        const u16* __restrict__ T1, const u16* __restrict__ T2,
        const u16* __restrict__ WT, const float* __restrict__ bsum,
        float* __restrict__ Cst, float* __restrict__ Hout, u16* __restrict__ HbNew,
        int writeH, int isFirst) {
    int tid = threadIdx.x;
    int w = tid >> 6, l = tid & 63;
    int m0 = blockIdx.x * GBM, n0 = blockIdx.y * GBN;
    int wm = (w >> 1) * 32, wn = (w & 1) * 64;   // wave sub-tile 32x64
    int rin = l & 15;
    int kc = (l >> 4) * 8;   // k-chunk within 32-wide window

    f32x4 acc[2][4] = {};

    // per-lane element offsets (A row stride F=256; B row stride 1024)
    size_t a0 = (size_t)(m0 + wm + rin) * F + kc;
    size_t a1 = a0 + (size_t)16 * F;
    size_t b0 = (size_t)(n0 + wn + rin) * 1024 + kc;
    size_t b1 = b0 + 16 * 1024;
    size_t b2 = b0 + 32 * 1024;
    size_t b3 = b0 + 48 * 1024;

    auto seg = [&](const u16* __restrict__ ab, const u16* __restrict__ bb) {
        #pragma unroll
        for (int kw = 0; kw < 8; kw++) {
            int k = kw * 32;
            bf16x8 av0 = *(const bf16x8*)(ab + a0 + k);
            bf16x8 av1 = *(const bf16x8*)(ab + a1 + k);
            bf16x8 bv0 = *(const bf16x8*)(bb + b0 + k);
            bf16x8 bv1 = *(const bf16x8*)(bb + b1 + k);
            bf16x8 bv2 = *(const bf16x8*)(bb + b2 + k);
            bf16x8 bv3 = *(const bf16x8*)(bb + b3 + k);
            acc[0][0] = __builtin_amdgcn_mfma_f32_16x16x32_bf16(av0, bv0, acc[0][0], 0, 0, 0);
            acc[0][1] = __builtin_amdgcn_mfma_f32_16x16x32_bf16(av0, bv1, acc[0][1], 0, 0, 0);
            acc[0][2] = __builtin_amdgcn_mfma_f32_16x16x32_bf16(av0, bv2, acc[0][2], 0, 0, 0);
            acc[0][3] = __builtin_amdgcn_mfma_f32_16x16x32_bf16(av0, bv3, acc[0][3], 0, 0, 0);
            acc[1][0] = __builtin_amdgcn_mfma_f32_16x16x32_bf16(av1, bv0, acc[1][0], 0, 0, 0);
            acc[1][1] = __builtin_amdgcn_mfma_f32_16x16x32_bf16(av1, bv1, acc[1][1], 0, 0, 0);
            acc[1][2] = __builtin_amdgcn_mfma_f32_16x16x32_bf16(av1, bv2, acc[1][2], 0, 0, 0);
            acc[1][3] = __builtin_amdgcn_mfma_f32_16x16x32_bf16(av1, bv3, acc[1][3], 0, 0, 0);
        }
    };
    // K segments: [Xt | Hb | Tx1 | Tx2], B cols k-offset +256 each
    seg(Xt, WT);
    seg(Hb, WT + 256);
    seg(T1, WT + 512);
    seg(T2, WT + 768);

    // LSTM epilogue. C/D layout: col = lane&15, row = (lane>>4)*4 + reg.
    // nf = gate (I,F,T,O); feature j = group*16 + cc, group = n0/64 + (w&1).
    int cr = (l >> 4) * 4, cc = l & 15;
    int feat = ((n0 >> 6) + (w & 1)) * 16 + cc;
    float bI = bsum[n0 + wn + 0  + cc];
    float bF = bsum[n0 + wn + 16 + cc];
    float bT = bsum[n0 + wn + 32 + cc];
    float bO = bsum[n0 + wn + 48 + cc];
    #pragma unroll
    for (int mf = 0; mf < 2; mf++) {
        #pragma unroll
        for (int r = 0; r < 4; r++) {
            int row = m0 + wm + mf * 16 + cr + r;
            size_t o = (size_t)row * F + feat;
            float I  = fsigmoid(acc[mf][0][r] + bI);
            float Fg = fsigmoid(acc[mf][1][r] + bF);
            float Tc = ftanh(acc[mf][2][r] + bT);
            float O  = fsigmoid(acc[mf][3][r] + bO);
            float cprev = isFirst ? 0.f : Cst[o];   // t=0: C starts at zero (buffer poisoned)
            float c  = Fg * cprev + I * Tc;
            Cst[o] = c;
            float h = O * ftanh(c);
            if (writeH) Hout[o] = h;   // fp32 H only needed at the final step
            HbNew[o] = f2bf(h);
        }
    }
}

// ---------------- launch ----------------

extern "C" void kernel_launch(void* const* d_in, const int* in_sizes, int n_in,
                              void* d_out, int out_size, void* d_ws, size_t ws_size,
                              hipStream_t stream) {
    const float* X   = (const float*)d_in[0];
    const float* ew  = (const float*)d_in[1];
    const float* Ws  = (const float*)d_in[2];
    const float* bs  = (const float*)d_in[3];
    const float* th  = (const float*)d_in[4];
    const float* cbs = (const float*)d_in[5];
    const int*   ei  = (const int*)d_in[6];
    const int* src = ei;
    const int* dst = ei + E_EDGES;

    float* H = (float*)d_out;               // N*F
    float* C = H + (size_t)N_NODES * F;     // N*F

    char* w = (char*)d_ws;
    size_t off = 0;
    auto alloc = [&](size_t bytes) {
        void* p = w + off;
        off += (bytes + 255) & ~(size_t)255;
        return p;
    };
    float* deg     = (float*)alloc(N_NODES * 4);
    int*   cnt     = (int*)  alloc(N_NODES * 4);
    int*   cursor  = (int*)  alloc(N_NODES * 4);
    int*   row_ptr = (int*)  alloc((N_NODES + 1) * 4);
    int*   csr_src = (int*)  alloc(E_EDGES * 4);
    float* csr_w   = (float*)alloc(E_EDGES * 4);
    u16*   WT      = (u16*)  alloc((size_t)1024 * 1024 * 2);
    float* bsum    = (float*)alloc(1024 * 4);
    u16*   Xtbf    = (u16*)  alloc((size_t)N_NODES * F * 2);
    u16*   Hb0     = (u16*)  alloc((size_t)N_NODES * F * 2);
    u16*   Hb1     = (u16*)  alloc((size_t)N_NODES * F * 2);
    u16*   Tx1bf   = (u16*)  alloc((size_t)N_NODES * F * 2);
    u16*   Tx2bf   = (u16*)  alloc((size_t)N_NODES * F * 2);

    hipMemsetAsync(Hb0, 0, (size_t)N_NODES * F * 2, stream);
    hipMemsetAsync(deg, 0, N_NODES * 4, stream);
    hipMemsetAsync(cnt, 0, N_NODES * 4, stream);
    hipMemsetAsync(cursor, 0, N_NODES * 4, stream);

    int eb = E_EDGES / 256;
    deg_kernel<<<eb, 256, 0, stream>>>(ew, src, deg);
    dis_kernel<<<N_NODES / 256, 256, 0, stream>>>(deg);
    count_kernel<<<eb, 256, 0, stream>>>(dst, cnt);
    scan_kernel<<<1, 256, 0, stream>>>(cnt, row_ptr);
    fill_csr<<<eb, 256, 0, stream>>>(src, dst, ew, deg, row_ptr, cursor, csr_src, csr_w);
    build_wcatT<<<(1024 * 1024) / 256, 256, 0, stream>>>(Ws, th, WT);
    build_bsum<<<4, 256, 0, stream>>>(bs, cbs, bsum);

    dim3 ggrid(N_NODES / GBM, ND / GBN);
    for (int t = 0; t < TSTEPS; t++) {
        u16* Hrd = (t & 1) ? Hb1 : Hb0;
        u16* Hwr = (t & 1) ? Hb0 : Hb1;
        // Tx1 = L_hat @ H   (+ fused X_t -> bf16 conversion)
        prop_kernel<<<N_NODES / 4, 256, 0, stream>>>(Hrd, nullptr, 1.f, row_ptr, csr_src,
                                                     csr_w, Tx1bf, X, t, Xtbf);
        // Tx2 = 2 * (L_hat @ Tx1) - H
        prop_kernel<<<N_NODES / 4, 256, 0, stream>>>(Tx1bf, Hrd, 2.f, row_ptr, csr_src,
                                                     csr_w, Tx2bf, nullptr, 0, nullptr);
        // gates + LSTM pointwise fused
        mfma_gemm<<<ggrid, 256, 0, stream>>>(Xtbf, Hrd, Tx1bf, Tx2bf, WT, bsum, C, H, Hwr,
                                             t == TSTEPS - 1 ? 1 : 0, t == 0 ? 1 : 0);
    }
}

// Round 7
// 1071.522 us; speedup vs baseline: 2.0303x; 2.0303x over previous
//
#include <hip/hip_runtime.h>
#include <cstddef>
#include <cstdint>

#define N_NODES 5120
#define E_EDGES 163840
#define F 256
#define TSTEPS 24
#define ND 1024          // GEMM N = 4*256 (gates, column-permuted)
#define XROWSTRIDE 6144  // T*F

typedef unsigned short u16;
typedef unsigned int u32;
typedef __bf16 bf16x8 __attribute__((ext_vector_type(8)));
typedef float f32x4 __attribute__((ext_vector_type(4)));

__device__ __forceinline__ u16 f2bf(float f) {
    u32 u = __float_as_uint(f);
    u = (u + 0x7FFFu + ((u >> 16) & 1u)) >> 16;  // round-to-nearest-even
    return (u16)u;
}
__device__ __forceinline__ float bf2f(u16 h) {
    return __uint_as_float((u32)h << 16);
}
__device__ __forceinline__ float fsigmoid(float x) {
    return 1.f / (1.f + __expf(-x));
}
__device__ __forceinline__ float ftanh(float x) {
    // tanh(x) = 1 - 2/(exp(2x)+1); saturates correctly for |x| large
    return 1.f - 2.f / (__expf(2.f * x) + 1.f);
}

// ---------------- graph preprocessing ----------------

__global__ void deg_kernel(const float* __restrict__ ew, const int* __restrict__ src,
                           float* __restrict__ deg) {
    int e = blockIdx.x * 256 + threadIdx.x;
    if (e < E_EDGES) atomicAdd(&deg[src[e]], ew[e]);
}

__global__ void dis_kernel(float* __restrict__ deg) {
    int n = blockIdx.x * 256 + threadIdx.x;
    if (n < N_NODES) {
        float d = deg[n];
        deg[n] = d > 0.f ? rsqrtf(d) : 0.f;
    }
}

__global__ void count_kernel(const int* __restrict__ dst, int* __restrict__ cnt) {
    int e = blockIdx.x * 256 + threadIdx.x;
    if (e < E_EDGES) atomicAdd(&cnt[dst[e]], 1);
}

// one block, 256 threads, 20 counts each (N_NODES = 256*20)
__global__ void scan_kernel(const int* __restrict__ cnt, int* __restrict__ row_ptr) {
    __shared__ int s[256];
    int tid = threadIdx.x;
    int base = tid * 20;
    int local[20];
    int sum = 0;
    #pragma unroll
    for (int i = 0; i < 20; i++) { local[i] = sum; sum += cnt[base + i]; }
    s[tid] = sum;
    __syncthreads();
    for (int off = 1; off < 256; off <<= 1) {
        int v = (tid >= off) ? s[tid - off] : 0;
        __syncthreads();
        s[tid] += v;
        __syncthreads();
    }
    int offset = (tid == 0) ? 0 : s[tid - 1];
    #pragma unroll
    for (int i = 0; i < 20; i++) row_ptr[base + i] = offset + local[i];
    if (tid == 0) row_ptr[N_NODES] = E_EDGES;
}

__global__ void fill_csr(const int* __restrict__ src, const int* __restrict__ dst,
                         const float* __restrict__ ew, const float* __restrict__ dis,
                         const int* __restrict__ row_ptr, int* __restrict__ cursor,
                         int* __restrict__ csr_src, float* __restrict__ csr_w) {
    int e = blockIdx.x * 256 + threadIdx.x;
    if (e >= E_EDGES) return;
    int s = src[e], d = dst[e];
    int pos = row_ptr[d] + atomicAdd(&cursor[d], 1);
    csr_src[pos] = s;
    // w_hat = (2/lambda_max)*(-dis[src]*w*dis[dst]); lambda_max=2 -> factor 1
    csr_w[pos] = -dis[s] * ew[e] * dis[d];
}

// Column permutation: col'(g, j) = (j>>4)*64 + g*16 + (j&15).
// Inverse: g = (c>>4)&3, j = (c>>6)*16 + (c&15).
// WT[c'][k] (bf16, k contiguous) = Wcat[k][g*256+j]
__global__ void build_wcatT(const float* __restrict__ Ws, const float* __restrict__ thetas,
                            u16* __restrict__ WT) {
    int idx = blockIdx.x * 256 + threadIdx.x;
    if (idx >= 1024 * 1024) return;
    int c = idx >> 10, k = idx & 1023;
    int g = (c >> 4) & 3;
    int j = (c >> 6) * 16 + (c & 15);
    float v;
    if (k < 256) {
        v = Ws[(g * 256 + k) * 256 + j];
    } else {
        int kc = (k >> 8) - 1;  // 0..2
        int rr = k & 255;
        v = thetas[((g * 3 + kc) * 256 + rr) * 256 + j];
    }
    WT[idx] = f2bf(v);
}

// bsum[c'] = bs[g*256+j] + cbs[g*256+j] in permuted column order
__global__ void build_bsum(const float* __restrict__ bs, const float* __restrict__ cbs,
                           float* __restrict__ bsum) {
    int c = blockIdx.x * 256 + threadIdx.x;
    if (c >= 1024) return;
    int g = (c >> 4) & 3;
    int j = (c >> 6) * 16 + (c & 15);
    bsum[c] = bs[g * 256 + j] + cbs[g * 256 + j];
}

// ---------------- prop: wave-per-node edge gather ----------------

__global__ __launch_bounds__(256) void prop_kernel(
        const u16* __restrict__ xin, const u16* __restrict__ sub, float scale,
        const int* __restrict__ row_ptr, const int* __restrict__ csr_src,
        const float* __restrict__ csr_w, u16* __restrict__ out_bf,
        const float* __restrict__ X, int t, u16* __restrict__ xt_out) {
    __shared__ int s_src[4][64];
    __shared__ float s_w[4][64];
    int wid = threadIdx.x >> 6, l = threadIdx.x & 63;
    int n = blockIdx.x * 4 + wid;
    int start = row_ptr[n], end = row_ptr[n + 1];
    float acc0 = 0.f, acc1 = 0.f, acc2 = 0.f, acc3 = 0.f;
    int fb = l * 4;  // this lane's 4 features
    for (int base = start; base < end; base += 64) {
        int chunk = min(64, end - base);
        if (l < chunk) {
            s_src[wid][l] = csr_src[base + l];
            s_w[wid][l] = csr_w[base + l];
        }
        #pragma unroll 4
        for (int i = 0; i < chunk; i++) {
            int s = s_src[wid][i];
            float wt = s_w[wid][i];
            ushort4 hv = *(const ushort4*)(xin + (size_t)s * F + fb);
            acc0 += wt * bf2f(hv.x);
            acc1 += wt * bf2f(hv.y);
            acc2 += wt * bf2f(hv.z);
            acc3 += wt * bf2f(hv.w);
        }
    }
    size_t o = (size_t)n * F + fb;
    float r0 = scale * acc0, r1 = scale * acc1, r2 = scale * acc2, r3 = scale * acc3;
    if (sub) {
        ushort4 sv = *(const ushort4*)(sub + o);
        r0 -= bf2f(sv.x); r1 -= bf2f(sv.y); r2 -= bf2f(sv.z); r3 -= bf2f(sv.w);
    }
    ushort4 ov;
    ov.x = f2bf(r0); ov.y = f2bf(r1); ov.z = f2bf(r2); ov.w = f2bf(r3);
    *(ushort4*)(out_bf + o) = ov;
    if (xt_out) {
        float4 xv = *(const float4*)(X + (size_t)n * XROWSTRIDE + (size_t)t * F + fb);
        ushort4 xo;
        xo.x = f2bf(xv.x); xo.y = f2bf(xv.y); xo.z = f2bf(xv.z); xo.w = f2bf(xv.w);
        *(ushort4*)(xt_out + o) = xo;
    }
}

// ---------------- fused bf16 MFMA GEMM + LSTM epilogue ----------------
// Tile 32x128 -> grid 160x8 = 1280 blocks = 5 blocks/CU (barrier overlap across
// independent blocks is the latency-hiding mechanism; R6 showed reg-streaming
// can't hide L2/LLC latency at low occupancy). Single-buffered LDS (R4-proven;
// R5's explicit dbuf regressed). 4 waves, wave sub-tile 16x64.
// A[5120,1024] = [Xt | Hb | Tx1 | Tx2] (bf16, row stride 256)
// WT = B^T in permuted column order (n-major, k-contig)
#define GBM 32
#define GBN 128
#define GBK 64

__global__ __launch_bounds__(256, 5) void mfma_gemm(
        const u16* __restrict__ Xt, const u16* __restrict__ Hb,
        const u16* __restrict__ T1, const u16* __restrict__ T2,
        const u16* __restrict__ WT, const float* __restrict__ bsum,
        float* __restrict__ Cst, float* __restrict__ Hout, u16* __restrict__ HbNew,
        int writeH, int isFirst) {
    __shared__ alignas(16) u16 As[GBM * GBK];
    __shared__ alignas(16) u16 Bs[GBN * GBK];
    int tid = threadIdx.x;
    int w = tid >> 6, l = tid & 63;
    int m0 = blockIdx.x * GBM, n0 = blockIdx.y * GBN;
    int wm = (w >> 1) * 16, wn = (w & 1) * 64;   // wave sub-tile 16x64

    // staging: chunk c covers LDS rows [c*8, c*8+8); lane l -> row c*8 + l/8.
    // rule #21: linear LDS dest + inverse-swizzled SOURCE col + swizzled READ.
    int srow = l >> 3;                // row & 7
    int scol = 8 * ((l & 7) ^ srow);  // source elem col for this lane's 16B

    f32x4 acc[4] = {};

    for (int k0 = 0; k0 < 1024; k0 += GBK) {
        int seg = k0 >> 8;
        const u16* ab = (seg == 0) ? Xt : (seg == 1) ? Hb : (seg == 2) ? T1 : T2;
        ab += (k0 & 255);
        const u16* bb = WT + k0;
        // A: 32 rows = 4 chunks (1 per wave)
        {
            int c = w;
            int row = c * 8 + srow;
            __builtin_amdgcn_global_load_lds(
                (const __attribute__((address_space(1))) u32*)(ab + (size_t)(m0 + row) * F + scol),
                (__attribute__((address_space(3))) u32*)(As + c * 512), 16, 0, 0);
        }
        // B: 128 rows = 16 chunks (4 per wave)
        #pragma unroll
        for (int i = 0; i < 4; i++) {
            int c = i * 4 + w;
            int row = c * 8 + srow;
            __builtin_amdgcn_global_load_lds(
                (const __attribute__((address_space(1))) u32*)(bb + (size_t)(n0 + row) * 1024 + scol),
                (__attribute__((address_space(3))) u32*)(Bs + c * 512), 16, 0, 0);
        }
        __syncthreads();
        #pragma unroll
        for (int kk = 0; kk < 2; kk++) {
            int kr = kk * 32 + (l >> 4) * 8;
            bf16x8 af;
            bf16x8 bfr[4];
            {
                int r = wm + (l & 15);
                af = *(const bf16x8*)(As + r * GBK + (kr ^ ((r & 7) << 3)));
            }
            #pragma unroll
            for (int nf = 0; nf < 4; nf++) {
                int r = wn + nf * 16 + (l & 15);
                bfr[nf] = *(const bf16x8*)(Bs + r * GBK + (kr ^ ((r & 7) << 3)));
            }
            #pragma unroll
            for (int nf = 0; nf < 4; nf++)
                acc[nf] = __builtin_amdgcn_mfma_f32_16x16x32_bf16(
                    af, bfr[nf], acc[nf], 0, 0, 0);
        }
        __syncthreads();
    }

    // LSTM epilogue. C/D layout: col = lane&15, row = (lane>>4)*4 + reg.
    // nf = gate (I,F,T,O); feature j = group*16 + cc, group = n0/64 + (w&1).
    int cr = (l >> 4) * 4, cc = l & 15;
    int feat = ((n0 >> 6) + (w & 1)) * 16 + cc;
    float bI = bsum[n0 + wn + 0  + cc];
    float bF = bsum[n0 + wn + 16 + cc];
    float bT = bsum[n0 + wn + 32 + cc];
    float bO = bsum[n0 + wn + 48 + cc];
    #pragma unroll
    for (int r = 0; r < 4; r++) {
        int row = m0 + wm + cr + r;
        size_t o = (size_t)row * F + feat;
        float I  = fsigmoid(acc[0][r] + bI);
        float Fg = fsigmoid(acc[1][r] + bF);
        float Tc = ftanh(acc[2][r] + bT);
        float O  = fsigmoid(acc[3][r] + bO);
        float cprev = isFirst ? 0.f : Cst[o];   // t=0: C starts at zero (buffer poisoned)
        float c  = Fg * cprev + I * Tc;
        Cst[o] = c;
        float h = O * ftanh(c);
        if (writeH) Hout[o] = h;   // fp32 H only needed at the final step
        HbNew[o] = f2bf(h);
    }
}

// ---------------- launch ----------------

extern "C" void kernel_launch(void* const* d_in, const int* in_sizes, int n_in,
                              void* d_out, int out_size, void* d_ws, size_t ws_size,
                              hipStream_t stream) {
    const float* X   = (const float*)d_in[0];
    const float* ew  = (const float*)d_in[1];
    const float* Ws  = (const float*)d_in[2];
    const float* bs  = (const float*)d_in[3];
    const float* th  = (const float*)d_in[4];
    const float* cbs = (const float*)d_in[5];
    const int*   ei  = (const int*)d_in[6];
    const int* src = ei;
    const int* dst = ei + E_EDGES;

    float* H = (float*)d_out;               // N*F
    float* C = H + (size_t)N_NODES * F;     // N*F

    char* w = (char*)d_ws;
    size_t off = 0;
    auto alloc = [&](size_t bytes) {
        void* p = w + off;
        off += (bytes + 255) & ~(size_t)255;
        return p;
    };
    float* deg     = (float*)alloc(N_NODES * 4);
    int*   cnt     = (int*)  alloc(N_NODES * 4);
    int*   cursor  = (int*)  alloc(N_NODES * 4);
    int*   row_ptr = (int*)  alloc((N_NODES + 1) * 4);
    int*   csr_src = (int*)  alloc(E_EDGES * 4);
    float* csr_w   = (float*)alloc(E_EDGES * 4);
    u16*   WT      = (u16*)  alloc((size_t)1024 * 1024 * 2);
    float* bsum    = (float*)alloc(1024 * 4);
    u16*   Xtbf    = (u16*)  alloc((size_t)N_NODES * F * 2);
    u16*   Hb0     = (u16*)  alloc((size_t)N_NODES * F * 2);
    u16*   Hb1     = (u16*)  alloc((size_t)N_NODES * F * 2);
    u16*   Tx1bf   = (u16*)  alloc((size_t)N_NODES * F * 2);
    u16*   Tx2bf   = (u16*)  alloc((size_t)N_NODES * F * 2);

    hipMemsetAsync(Hb0, 0, (size_t)N_NODES * F * 2, stream);
    hipMemsetAsync(deg, 0, N_NODES * 4, stream);
    hipMemsetAsync(cnt, 0, N_NODES * 4, stream);
    hipMemsetAsync(cursor, 0, N_NODES * 4, stream);

    int eb = E_EDGES / 256;
    deg_kernel<<<eb, 256, 0, stream>>>(ew, src, deg);
    dis_kernel<<<N_NODES / 256, 256, 0, stream>>>(deg);
    count_kernel<<<eb, 256, 0, stream>>>(dst, cnt);
    scan_kernel<<<1, 256, 0, stream>>>(cnt, row_ptr);
    fill_csr<<<eb, 256, 0, stream>>>(src, dst, ew, deg, row_ptr, cursor, csr_src, csr_w);
    build_wcatT<<<(1024 * 1024) / 256, 256, 0, stream>>>(Ws, th, WT);
    build_bsum<<<4, 256, 0, stream>>>(bs, cbs, bsum);

    dim3 ggrid(N_NODES / GBM, ND / GBN);
    for (int t = 0; t < TSTEPS; t++) {
        u16* Hrd = (t & 1) ? Hb1 : Hb0;
        u16* Hwr = (t & 1) ? Hb0 : Hb1;
        // Tx1 = L_hat @ H   (+ fused X_t -> bf16 conversion)
        prop_kernel<<<N_NODES / 4, 256, 0, stream>>>(Hrd, nullptr, 1.f, row_ptr, csr_src,
                                                     csr_w, Tx1bf, X, t, Xtbf);
        // Tx2 = 2 * (L_hat @ Tx1) - H
        prop_kernel<<<N_NODES / 4, 256, 0, stream>>>(Tx1bf, Hrd, 2.f, row_ptr, csr_src,
                                                     csr_w, Tx2bf, nullptr, 0, nullptr);
        // gates + LSTM pointwise fused
        mfma_gemm<<<ggrid, 256, 0, stream>>>(Xtbf, Hrd, Tx1bf, Tx2bf, WT, bsum, C, H, Hwr,
                                             t == TSTEPS - 1 ? 1 : 0, t == 0 ? 1 : 0);
    }
}

// Round 8
// 1031.002 us; speedup vs baseline: 2.1101x; 1.0393x over previous
//
#include <hip/hip_runtime.h>
#include <cstddef>
#include <cstdint>

#define N_NODES 5120
#define E_EDGES 163840
#define F 256
#define TSTEPS 24
#define ND 1024          // GEMM N = 4*256 (gates, column-permuted)
#define XROWSTRIDE 6144  // T*F

typedef unsigned short u16;
typedef unsigned int u32;
typedef __bf16 bf16x8 __attribute__((ext_vector_type(8)));
typedef float f32x4 __attribute__((ext_vector_type(4)));

__device__ __forceinline__ u16 f2bf(float f) {
    u32 u = __float_as_uint(f);
    u = (u + 0x7FFFu + ((u >> 16) & 1u)) >> 16;  // round-to-nearest-even
    return (u16)u;
}
__device__ __forceinline__ float bf2f(u16 h) {
    return __uint_as_float((u32)h << 16);
}
__device__ __forceinline__ float fsigmoid(float x) {
    return 1.f / (1.f + __expf(-x));
}
__device__ __forceinline__ float ftanh(float x) {
    // tanh(x) = 1 - 2/(exp(2x)+1); saturates correctly for |x| large
    return 1.f - 2.f / (__expf(2.f * x) + 1.f);
}

// ---------------- graph preprocessing ----------------

__global__ void deg_kernel(const float* __restrict__ ew, const int* __restrict__ src,
                           float* __restrict__ deg) {
    int e = blockIdx.x * 256 + threadIdx.x;
    if (e < E_EDGES) atomicAdd(&deg[src[e]], ew[e]);
}

__global__ void dis_kernel(float* __restrict__ deg) {
    int n = blockIdx.x * 256 + threadIdx.x;
    if (n < N_NODES) {
        float d = deg[n];
        deg[n] = d > 0.f ? rsqrtf(d) : 0.f;
    }
}

__global__ void count_kernel(const int* __restrict__ dst, int* __restrict__ cnt) {
    int e = blockIdx.x * 256 + threadIdx.x;
    if (e < E_EDGES) atomicAdd(&cnt[dst[e]], 1);
}

// one block, 256 threads, 20 counts each (N_NODES = 256*20)
__global__ void scan_kernel(const int* __restrict__ cnt, int* __restrict__ row_ptr) {
    __shared__ int s[256];
    int tid = threadIdx.x;
    int base = tid * 20;
    int local[20];
    int sum = 0;
    #pragma unroll
    for (int i = 0; i < 20; i++) { local[i] = sum; sum += cnt[base + i]; }
    s[tid] = sum;
    __syncthreads();
    for (int off = 1; off < 256; off <<= 1) {
        int v = (tid >= off) ? s[tid - off] : 0;
        __syncthreads();
        s[tid] += v;
        __syncthreads();
    }
    int offset = (tid == 0) ? 0 : s[tid - 1];
    #pragma unroll
    for (int i = 0; i < 20; i++) row_ptr[base + i] = offset + local[i];
    if (tid == 0) row_ptr[N_NODES] = E_EDGES;
}

__global__ void fill_csr(const int* __restrict__ src, const int* __restrict__ dst,
                         const float* __restrict__ ew, const float* __restrict__ dis,
                         const int* __restrict__ row_ptr, int* __restrict__ cursor,
                         int* __restrict__ csr_src, float* __restrict__ csr_w) {
    int e = blockIdx.x * 256 + threadIdx.x;
    if (e >= E_EDGES) return;
    int s = src[e], d = dst[e];
    int pos = row_ptr[d] + atomicAdd(&cursor[d], 1);
    csr_src[pos] = s;
    // w_hat = (2/lambda_max)*(-dis[src]*w*dis[dst]); lambda_max=2 -> factor 1
    csr_w[pos] = -dis[s] * ew[e] * dis[d];
}

// Column permutation: col'(g, j) = (j>>4)*64 + g*16 + (j&15).
// Inverse: g = (c>>4)&3, j = (c>>6)*16 + (c&15).
// WT[c'][k] (bf16, k contiguous) = Wcat[k][g*256+j]
__global__ void build_wcatT(const float* __restrict__ Ws, const float* __restrict__ thetas,
                            u16* __restrict__ WT) {
    int idx = blockIdx.x * 256 + threadIdx.x;
    if (idx >= 1024 * 1024) return;
    int c = idx >> 10, k = idx & 1023;
    int g = (c >> 4) & 3;
    int j = (c >> 6) * 16 + (c & 15);
    float v;
    if (k < 256) {
        v = Ws[(g * 256 + k) * 256 + j];
    } else {
        int kc = (k >> 8) - 1;  // 0..2
        int rr = k & 255;
        v = thetas[((g * 3 + kc) * 256 + rr) * 256 + j];
    }
    WT[idx] = f2bf(v);
}

// bsum[c'] = bs[g*256+j] + cbs[g*256+j] in permuted column order
__global__ void build_bsum(const float* __restrict__ bs, const float* __restrict__ cbs,
                           float* __restrict__ bsum) {
    int c = blockIdx.x * 256 + threadIdx.x;
    if (c >= 1024) return;
    int g = (c >> 4) & 3;
    int j = (c >> 6) * 16 + (c & 15);
    bsum[c] = bs[g * 256 + j] + cbs[g * 256 + j];
}

// ---------------- prop: wave-per-node edge gather ----------------

__global__ __launch_bounds__(256) void prop_kernel(
        const u16* __restrict__ xin, const u16* __restrict__ sub, float scale,
        const int* __restrict__ row_ptr, const int* __restrict__ csr_src,
        const float* __restrict__ csr_w, u16* __restrict__ out_bf,
        const float* __restrict__ X, int t, u16* __restrict__ xt_out) {
    __shared__ int s_src[4][64];
    __shared__ float s_w[4][64];
    int wid = threadIdx.x >> 6, l = threadIdx.x & 63;
    int n = blockIdx.x * 4 + wid;
    int start = row_ptr[n], end = row_ptr[n + 1];
    float acc0 = 0.f, acc1 = 0.f, acc2 = 0.f, acc3 = 0.f;
    int fb = l * 4;  // this lane's 4 features
    for (int base = start; base < end; base += 64) {
        int chunk = min(64, end - base);
        if (l < chunk) {
            s_src[wid][l] = csr_src[base + l];
            s_w[wid][l] = csr_w[base + l];
        }
        #pragma unroll 4
        for (int i = 0; i < chunk; i++) {
            int s = s_src[wid][i];
            float wt = s_w[wid][i];
            ushort4 hv = *(const ushort4*)(xin + (size_t)s * F + fb);
            acc0 += wt * bf2f(hv.x);
            acc1 += wt * bf2f(hv.y);
            acc2 += wt * bf2f(hv.z);
            acc3 += wt * bf2f(hv.w);
        }
    }
    size_t o = (size_t)n * F + fb;
    float r0 = scale * acc0, r1 = scale * acc1, r2 = scale * acc2, r3 = scale * acc3;
    if (sub) {
        ushort4 sv = *(const ushort4*)(sub + o);
        r0 -= bf2f(sv.x); r1 -= bf2f(sv.y); r2 -= bf2f(sv.z); r3 -= bf2f(sv.w);
    }
    ushort4 ov;
    ov.x = f2bf(r0); ov.y = f2bf(r1); ov.z = f2bf(r2); ov.w = f2bf(r3);
    *(ushort4*)(out_bf + o) = ov;
    if (xt_out) {
        float4 xv = *(const float4*)(X + (size_t)n * XROWSTRIDE + (size_t)t * F + fb);
        ushort4 xo;
        xo.x = f2bf(xv.x); xo.y = f2bf(xv.y); xo.z = f2bf(xv.z); xo.w = f2bf(xv.w);
        *(ushort4*)(xt_out + o) = xo;
    }
}

// ---------------- fused bf16 MFMA GEMM + LSTM epilogue ----------------
// Tile 64x128 (R4-proven best), grid 80x8 = 640 blocks.
// T4 counted-vmcnt double-buffer: raw s_barrier + `s_waitcnt vmcnt(6)` so the
// prefetched tile's 6 loads/wave stay in flight ACROSS the barrier (no vmcnt(0)
// drain in the main loop). Correctness: each wave retires its own tile-k loads
// before barrier B => after B, all waves' tile-k LDS writes are visible; buffer
// overwrite happens only after barrier A (post compute(k-1)).
// A[5120,1024] = [Xt | Hb | Tx1 | Tx2] (bf16, row stride 256)
// WT = B^T in permuted column order (n-major, k-contig)
#define GBM 64
#define GBN 128
#define GBK 64
#define NKS 16  // 1024 / GBK

__global__ __launch_bounds__(256) void mfma_gemm(
        const u16* __restrict__ Xt, const u16* __restrict__ Hb,
        const u16* __restrict__ T1, const u16* __restrict__ T2,
        const u16* __restrict__ WT, const float* __restrict__ bsum,
        float* __restrict__ Cst, float* __restrict__ Hout, u16* __restrict__ HbNew,
        int writeH, int isFirst) {
    __shared__ alignas(16) u16 As[2][GBM * GBK];
    __shared__ alignas(16) u16 Bs[2][GBN * GBK];
    int tid = threadIdx.x;
    int w = tid >> 6, l = tid & 63;
    int m0 = blockIdx.x * GBM, n0 = blockIdx.y * GBN;
    int wm = (w >> 1) * 32, wn = (w & 1) * 64;   // wave sub-tile 32x64

    // staging: chunk c covers LDS rows [c*8, c*8+8); lane l -> row c*8 + l/8.
    // rule #21: linear LDS dest + inverse-swizzled SOURCE col + swizzled READ.
    int srow = l >> 3;                // row & 7
    int scol = 8 * ((l & 7) ^ srow);  // source elem col for this lane's 16B

    f32x4 acc[2][4] = {};

    auto stage = [&](int ks, int buf) {
        int k0 = ks * GBK;
        int seg = k0 >> 8;
        const u16* ab = (seg == 0) ? Xt : (seg == 1) ? Hb : (seg == 2) ? T1 : T2;
        ab += (k0 & 255);
        const u16* bb = WT + k0;
        u16* Asb = &As[buf][0];
        u16* Bsb = &Bs[buf][0];
        // A: 64 rows = 8 chunks (2 per wave)
        #pragma unroll
        for (int i = 0; i < 2; i++) {
            int c = i * 4 + w;
            int row = c * 8 + srow;
            __builtin_amdgcn_global_load_lds(
                (const __attribute__((address_space(1))) u32*)(ab + (size_t)(m0 + row) * F + scol),
                (__attribute__((address_space(3))) u32*)(Asb + c * 512), 16, 0, 0);
        }
        // B: 128 rows = 16 chunks (4 per wave)
        #pragma unroll
        for (int i = 0; i < 4; i++) {
            int c = i * 4 + w;
            int row = c * 8 + srow;
            __builtin_amdgcn_global_load_lds(
                (const __attribute__((address_space(1))) u32*)(bb + (size_t)(n0 + row) * 1024 + scol),
                (__attribute__((address_space(3))) u32*)(Bsb + c * 512), 16, 0, 0);
        }
    };

    stage(0, 0);  // prologue: tile 0 in flight (6 loads/wave)

    for (int ks = 0; ks < NKS; ks++) {
        // barrier A: all waves done computing tile ks-1 -> safe to overwrite buf[(ks+1)&1]
        __builtin_amdgcn_s_barrier();
        if (ks < NKS - 1) {
            stage(ks + 1, (ks + 1) & 1);               // 6 more loads/wave in flight
            asm volatile("s_waitcnt vmcnt(6)" ::: "memory");  // retire tile-ks loads only
        } else {
            asm volatile("s_waitcnt vmcnt(0)" ::: "memory");  // tail: only tile-15 outstanding
        }
        // barrier B: every wave has retired its tile-ks loads -> LDS tile complete
        __builtin_amdgcn_s_barrier();
        __builtin_amdgcn_sched_barrier(0);

        const u16* Asb = &As[ks & 1][0];
        const u16* Bsb = &Bs[ks & 1][0];
        #pragma unroll
        for (int kk = 0; kk < 2; kk++) {
            int kr = kk * 32 + (l >> 4) * 8;
            bf16x8 af[2], bfr[4];
            #pragma unroll
            for (int mf = 0; mf < 2; mf++) {
                int r = wm + mf * 16 + (l & 15);
                af[mf] = *(const bf16x8*)(Asb + r * GBK + (kr ^ ((r & 7) << 3)));
            }
            #pragma unroll
            for (int nf = 0; nf < 4; nf++) {
                int r = wn + nf * 16 + (l & 15);
                bfr[nf] = *(const bf16x8*)(Bsb + r * GBK + (kr ^ ((r & 7) << 3)));
            }
            #pragma unroll
            for (int mf = 0; mf < 2; mf++)
                #pragma unroll
                for (int nf = 0; nf < 4; nf++)
                    acc[mf][nf] = __builtin_amdgcn_mfma_f32_16x16x32_bf16(
                        af[mf], bfr[nf], acc[mf][nf], 0, 0, 0);
        }
    }

    // LSTM epilogue. C/D layout: col = lane&15, row = (lane>>4)*4 + reg.
    // nf = gate (I,F,T,O); feature j = group*16 + cc, group = n0/64 + (w&1).
    int cr = (l >> 4) * 4, cc = l & 15;
    int feat = ((n0 >> 6) + (w & 1)) * 16 + cc;
    float bI = bsum[n0 + wn + 0  + cc];
    float bF = bsum[n0 + wn + 16 + cc];
    float bT = bsum[n0 + wn + 32 + cc];
    float bO = bsum[n0 + wn + 48 + cc];
    #pragma unroll
    for (int mf = 0; mf < 2; mf++) {
        #pragma unroll
        for (int r = 0; r < 4; r++) {
            int row = m0 + wm + mf * 16 + cr + r;
            size_t o = (size_t)row * F + feat;
            float I  = fsigmoid(acc[mf][0][r] + bI);
            float Fg = fsigmoid(acc[mf][1][r] + bF);
            float Tc = ftanh(acc[mf][2][r] + bT);
            float O  = fsigmoid(acc[mf][3][r] + bO);
            float cprev = isFirst ? 0.f : Cst[o];   // t=0: C starts at zero (buffer poisoned)
            float c  = Fg * cprev + I * Tc;
            Cst[o] = c;
            float h = O * ftanh(c);
            if (writeH) Hout[o] = h;   // fp32 H only needed at the final step
            HbNew[o] = f2bf(h);
        }
    }
}

// ---------------- launch ----------------

extern "C" void kernel_launch(void* const* d_in, const int* in_sizes, int n_in,
                              void* d_out, int out_size, void* d_ws, size_t ws_size,
                              hipStream_t stream) {
    const float* X   = (const float*)d_in[0];
    const float* ew  = (const float*)d_in[1];
    const float* Ws  = (const float*)d_in[2];
    const float* bs  = (const float*)d_in[3];
    const float* th  = (const float*)d_in[4];
    const float* cbs = (const float*)d_in[5];
    const int*   ei  = (const int*)d_in[6];
    const int* src = ei;
    const int* dst = ei + E_EDGES;

    float* H = (float*)d_out;               // N*F
    float* C = H + (size_t)N_NODES * F;     // N*F

    char* w = (char*)d_ws;
    size_t off = 0;
    auto alloc = [&](size_t bytes) {
        void* p = w + off;
        off += (bytes + 255) & ~(size_t)255;
        return p;
    };
    float* deg     = (float*)alloc(N_NODES * 4);
    int*   cnt     = (int*)  alloc(N_NODES * 4);
    int*   cursor  = (int*)  alloc(N_NODES * 4);
    int*   row_ptr = (int*)  alloc((N_NODES + 1) * 4);
    int*   csr_src = (int*)  alloc(E_EDGES * 4);
    float* csr_w   = (float*)alloc(E_EDGES * 4);
    u16*   WT      = (u16*)  alloc((size_t)1024 * 1024 * 2);
    float* bsum    = (float*)alloc(1024 * 4);
    u16*   Xtbf    = (u16*)  alloc((size_t)N_NODES * F * 2);
    u16*   Hb0     = (u16*)  alloc((size_t)N_NODES * F * 2);
    u16*   Hb1     = (u16*)  alloc((size_t)N_NODES * F * 2);
    u16*   Tx1bf   = (u16*)  alloc((size_t)N_NODES * F * 2);
    u16*   Tx2bf   = (u16*)  alloc((size_t)N_NODES * F * 2);

    hipMemsetAsync(Hb0, 0, (size_t)N_NODES * F * 2, stream);
    hipMemsetAsync(deg, 0, N_NODES * 4, stream);
    hipMemsetAsync(cnt, 0, N_NODES * 4, stream);
    hipMemsetAsync(cursor, 0, N_NODES * 4, stream);

    int eb = E_EDGES / 256;
    deg_kernel<<<eb, 256, 0, stream>>>(ew, src, deg);
    dis_kernel<<<N_NODES / 256, 256, 0, stream>>>(deg);
    count_kernel<<<eb, 256, 0, stream>>>(dst, cnt);
    scan_kernel<<<1, 256, 0, stream>>>(cnt, row_ptr);
    fill_csr<<<eb, 256, 0, stream>>>(src, dst, ew, deg, row_ptr, cursor, csr_src, csr_w);
    build_wcatT<<<(1024 * 1024) / 256, 256, 0, stream>>>(Ws, th, WT);
    build_bsum<<<4, 256, 0, stream>>>(bs, cbs, bsum);

    dim3 ggrid(N_NODES / GBM, ND / GBN);
    for (int t = 0; t < TSTEPS; t++) {
        u16* Hrd = (t & 1) ? Hb1 : Hb0;
        u16* Hwr = (t & 1) ? Hb0 : Hb1;
        // Tx1 = L_hat @ H   (+ fused X_t -> bf16 conversion)
        prop_kernel<<<N_NODES / 4, 256, 0, stream>>>(Hrd, nullptr, 1.f, row_ptr, csr_src,
                                                     csr_w, Tx1bf, X, t, Xtbf);
        // Tx2 = 2 * (L_hat @ Tx1) - H
        prop_kernel<<<N_NODES / 4, 256, 0, stream>>>(Tx1bf, Hrd, 2.f, row_ptr, csr_src,
                                                     csr_w, Tx2bf, nullptr, 0, nullptr);
        // gates + LSTM pointwise fused
        mfma_gemm<<<ggrid, 256, 0, stream>>>(Xtbf, Hrd, Tx1bf, Tx2bf, WT, bsum, C, H, Hwr,
                                             t == TSTEPS - 1 ? 1 : 0, t == 0 ? 1 : 0);
    }
}